// Round 9
// baseline (232.395 us; speedup 1.0000x reference)
//
#include <hip/hip_runtime.h>
#include <hip/hip_bf16.h>

// SirenLinear: out[b,r] = sum_c x[b,c] * W[r,c] + bias[r]
//   W[r,c] = b3 + h2 . W3,  h2 = sin(30*(W2 h1 + b2)),  h1 = sin(30*(W1 e + b1))
//
// Round-15 (post-mortem r8: fused ~34us vs ~5us of VALU/DS/MFMA issue ->
// the unexplained time fits a slow trans pipe (~16cy/wave v_sin). The one
// prior sin-halving attempt (r3) was masked by its own VMEM latency bug,
// which the r4 LDS tiling has since fixed. So: halve the sins, properly):
//  * layer-1 h1 via sin/cos product identity, tables as {sin,cos} float2
//    staged in LDS (zrow 8KB linear, zcol 16KB chunk-XOR-swizzled).
//    h1 = sr*cc + cr*sc: 2 VALU, 0 trans. Deletes 64 of 128 sins/point.
//  * h2 W3-dot: 4 partial accumulators (breaks 16-deep serial fma chain).
//  * MFMA-swapped layout (r8), cast T14 split (r7), gemm/launch unchanged.

typedef __attribute__((ext_vector_type(8))) short bf16x8;
typedef __attribute__((ext_vector_type(4))) float f32x4;

#define SIN_SCALE 4.77464829275686f   // 30 / (2*pi)

__device__ __forceinline__ unsigned short f2bf(float f) {
    union { float f; unsigned u; } v; v.f = f;
    unsigned r = v.u + 0x7fffu + ((v.u >> 16) & 1u);   // RNE
    return (unsigned short)(r >> 16);
}

// pack 2 floats -> 2 bf16 by truncation (cheap; RNE kept for final store)
__device__ __forceinline__ unsigned pktrunc(float a, float b) {
    union { float f; unsigned u; } x, y; x.f = a; y.f = b;
    return (x.u >> 16) | (y.u & 0xffff0000u);
}

// sin/cos(2*pi*x) -- raw v_sin/v_cos, valid |x| <= 256 revs (here |x| <= ~14)
__device__ __forceinline__ float sinrev(float x) {
    return __builtin_amdgcn_sinf(x);
}
__device__ __forceinline__ float cosrev(float x) {
    return __builtin_amdgcn_cosf(x);
}

__device__ __forceinline__ void async_ld16(const void* g, void* l) {
    __builtin_amdgcn_global_load_lds(
        (__attribute__((address_space(1))) void*)g,
        (__attribute__((address_space(3))) void*)l, 16, 0, 0);
}

// ---------------- stage 0: layer-1 separable sin/cos tables ----------------
// zrow[r][j] = S*(W1[j,:].e(r,0)+b1[j]);  zcol[c][j] = S*(W1[j,:].(e(0,c)-e(0,0)))
// SCrow[r][j] = {sin(2pi zrow), cos(2pi zrow)};  SCcol likewise.
// h1 = sin(2pi(zr+zc)) = sr*cc + cr*sc  (verified numerics: r3 passed).
__global__ __launch_bounds__(256) void tables_kernel(
        const float* __restrict__ ec,
        const float* __restrict__ W1, const float* __restrict__ b1,
        float2* __restrict__ SCrow, float2* __restrict__ SCcol) {
    int idx = blockIdx.x * 256 + threadIdx.x;    // 0..131071
    int j = idx & 63;
    int t = idx >> 6;                            // 0..2047
    const float* wr = W1 + j * 18;
    if (t < 1024) {
        const float* pe = ec + (long)t * 1024 * 18;   // point (r=t, c=0)
        float z = b1[j];
        #pragma unroll
        for (int i = 0; i < 18; ++i) z += wr[i] * pe[i];
        z *= SIN_SCALE;
        SCrow[t * 64 + j] = make_float2(sinrev(z), cosrev(z));
    } else {
        int c = t - 1024;
        const float* pe = ec + (long)c * 18;          // point (r=0, c)
        float z = 0.f;
        #pragma unroll
        for (int i = 0; i < 18; ++i) z += wr[i] * (pe[i] - ec[i]);
        z *= SIN_SCALE;
        SCcol[c * 64 + j] = make_float2(sinrev(z), cosrev(z));
    }
}

// ---------------- stage 1: [generate W, LDS-tiled] + [x cast share] --------
// 2048 blocks, ALL identical: block sb covers W rows [br*16,+16) x cols
// [bc*32,+32) AND casts x float4s [sb*1024,+1024) (T14 split).
//
// LDS: SCrow tile 16x64 float2 (8KB, linear); SCcol tile 32x64 float2
// (16KB). SCcol rows = 512B = 32 chunks of 16B; physical chunk p holds
// logical chunk (p&16) | ((p&15) ^ (col&15)) (source pre-swizzled,
// m104/m173). Compute read: lane (ln,kq), col cl=ct*16+ln reads logical
// chunks kq*4+t (zc0) / 16+kq*4+t (zc1); phys spread over 16 distinct
// chunks across the 16 lanes -> banks phys*4%32: 2-way = free (m136).
// h1 frag (MFMA B operand): lane ln = point, k = kc*32+kq*8+j.
// W2 frag (A operand): lane ln = unit-within-subtile. C/D [m89/m91]:
// n=ln=point, m=kq*4+rg -> unit=nt*16+kq*4+rg. acc init = S*b2[unit];
// layer-2: in-lane 16 sin+fma (4 partials), ^32/^16 shfl, kq==0 stores.
__global__ __launch_bounds__(256, 4) void fused_cast_siren(
        const float4* __restrict__ x, unsigned short* __restrict__ xb,
        const float2* __restrict__ SCrow, const float2* __restrict__ SCcol,
        const float* __restrict__ W2, const float* __restrict__ b2,
        const float* __restrict__ W3, const float* __restrict__ b3,
        unsigned short* __restrict__ Wout) {
    __shared__ __align__(16) float2 zrow_l[16 * 64];   // 8 KB, linear
    __shared__ __align__(16) float2 zcol_l[32 * 64];   // 16 KB, chunk-swizzled

    int tid  = threadIdx.x;
    int sb   = blockIdx.x;             // 0..2047
    int lane = tid & 63;
    int wv   = tid >> 6;
    int ln   = lane & 15;
    int kq   = lane >> 4;

    int br = sb & 63;                  // row-tile: rows [br*16, br*16+16)
    int bc = sb >> 6;                  // col-tile: cols [bc*32, bc*32+32)

    long ci = (long)sb * 1024 + tid;

    // ---- cast half 1: issue loads (latency hides under table staging) ----
    float4 cv0 = x[ci];
    float4 cv1 = x[ci + 256];

    // ---- stage tables into LDS (6 x global_load_lds per thread) ----
    {
        const float* rs = (const float*)SCrow + (long)br * 16 * 128;
        #pragma unroll
        for (int q = 0; q < 2; ++q) {
            int idx = q * 256 + tid;                  // chunk 0..511
            async_ld16(rs + idx * 4, (float*)zrow_l + (q * 256 + wv * 64) * 4);
        }
        #pragma unroll
        for (int q = 0; q < 4; ++q) {
            int P  = q * 256 + tid;                   // physical chunk 0..1023
            int cr = P >> 5;                          // local col 0..31
            int pc = P & 31;
            int lc = (pc & 16) | ((pc & 15) ^ (cr & 15));  // logical chunk
            const float* src = (const float*)SCcol + (long)(bc * 32 + cr) * 128 + lc * 4;
            async_ld16(src, (float*)zcol_l + (q * 256 + wv * 64) * 4);
        }
    }

    // ---- cast half 1: cvt + store; half 2: issue loads ----
    {
        ushort4 o;
        o.x = f2bf(cv0.x); o.y = f2bf(cv0.y); o.z = f2bf(cv0.z); o.w = f2bf(cv0.w);
        *(ushort4*)(xb + ci * 4) = o;
        o.x = f2bf(cv1.x); o.y = f2bf(cv1.y); o.z = f2bf(cv1.z); o.w = f2bf(cv1.w);
        *(ushort4*)(xb + (ci + 256) * 4) = o;
    }
    float4 cv2 = x[ci + 512];
    float4 cv3 = x[ci + 768];

    // ---- preload A-frags of S*W2 (trunc bf16); S*b2 and W3 as float4 ----
    bf16x8 wfrag[2][4];
    #pragma unroll
    for (int kc = 0; kc < 2; ++kc)
        #pragma unroll
        for (int nt = 0; nt < 4; ++nt) {
            const float* src = W2 + (nt * 16 + ln) * 64 + kc * 32 + kq * 8;
            union { bf16x8 v; unsigned u[4]; } tmp;
            #pragma unroll
            for (int q = 0; q < 4; ++q)
                tmp.u[q] = pktrunc(SIN_SCALE * src[2*q], SIN_SCALE * src[2*q + 1]);
            wfrag[kc][nt] = tmp.v;
        }
    f32x4 b2x4[4], w3x4[4];
    #pragma unroll
    for (int nt = 0; nt < 4; ++nt) {
        float4 bb = *(const float4*)(b2 + nt * 16 + kq * 4);
        float4 ww = *(const float4*)(W3 + nt * 16 + kq * 4);
        b2x4[nt][0] = SIN_SCALE * bb.x; b2x4[nt][1] = SIN_SCALE * bb.y;
        b2x4[nt][2] = SIN_SCALE * bb.z; b2x4[nt][3] = SIN_SCALE * bb.w;
        w3x4[nt][0] = ww.x; w3x4[nt][1] = ww.y; w3x4[nt][2] = ww.z; w3x4[nt][3] = ww.w;
    }
    float b3s = b3[0];

    // ---- cast half 2: cvt + store (regs die before compute phase) ----
    {
        ushort4 o;
        o.x = f2bf(cv2.x); o.y = f2bf(cv2.y); o.z = f2bf(cv2.z); o.w = f2bf(cv2.w);
        *(ushort4*)(xb + (ci + 512) * 4) = o;
        o.x = f2bf(cv3.x); o.y = f2bf(cv3.y); o.z = f2bf(cv3.z); o.w = f2bf(cv3.w);
        *(ushort4*)(xb + (ci + 768) * 4) = o;
    }

    __syncthreads();                    // tables resident in LDS

    #pragma unroll
    for (int lr4 = 0; lr4 < 4; ++lr4) {
        int lr = wv * 4 + lr4;                            // local row 0..15
        const float2* zb = zrow_l + lr * 64 + kq * 8;     // broadcast reads
        float sr0[8], cr0[8], sr1[8], cr1[8];
        #pragma unroll
        for (int j = 0; j < 8; ++j) {
            float2 t0 = zb[j];      sr0[j] = t0.x; cr0[j] = t0.y;
            float2 t1 = zb[32 + j]; sr1[j] = t1.x; cr1[j] = t1.y;
        }

        #pragma unroll
        for (int ct = 0; ct < 2; ++ct) {
            int cl = ct * 16 + ln;                        // local col 0..31
            const float* cb = (const float*)zcol_l + cl * 128;
            int sx = cl & 15;
            float sc0[16], sc1[16];                       // 8 x {s,c} each
            #pragma unroll
            for (int t = 0; t < 4; ++t) {
                int p0 = ((kq * 4 + t) ^ sx) * 4;
                int p1 = (16 | ((kq * 4 + t) ^ sx)) * 4;
                #pragma unroll
                for (int e = 0; e < 4; ++e) {
                    sc0[t * 4 + e] = cb[p0 + e];
                    sc1[t * 4 + e] = cb[p1 + e];
                }
            }

            // h1 = sr*cc + cr*sc  (2 VALU, 0 trans per element)
            float s0[8], s1[8];
            #pragma unroll
            for (int j = 0; j < 8; ++j) {
                s0[j] = fmaf(sr0[j], sc0[2*j + 1], cr0[j] * sc0[2*j]);
                s1[j] = fmaf(sr1[j], sc1[2*j + 1], cr1[j] * sc1[2*j]);
            }
            union { bf16x8 v; unsigned u[4]; } a0, a1;
            #pragma unroll
            for (int q = 0; q < 4; ++q) {
                a0.u[q] = pktrunc(s0[2*q], s0[2*q + 1]);
                a1.u[q] = pktrunc(s1[2*q], s1[2*q + 1]);
            }

            // acc init = S*b2[unit]; D[m=unit-in-subtile, n=point]
            f32x4 acc[4];
            #pragma unroll
            for (int nt = 0; nt < 4; ++nt) acc[nt] = b2x4[nt];
            #pragma unroll
            for (int nt = 0; nt < 4; ++nt) {
                acc[nt] = __builtin_amdgcn_mfma_f32_16x16x32_bf16(wfrag[0][nt], a0.v, acc[nt], 0, 0, 0);
                acc[nt] = __builtin_amdgcn_mfma_f32_16x16x32_bf16(wfrag[1][nt], a1.v, acc[nt], 0, 0, 0);
            }

            // layer-2: in-lane 16 sin+fma with 4 partial sums, reduce over kq
            float ps[4] = {0.f, 0.f, 0.f, 0.f};
            #pragma unroll
            for (int nt = 0; nt < 4; ++nt)
                #pragma unroll
                for (int rg = 0; rg < 4; ++rg)
                    ps[rg] = fmaf(w3x4[nt][rg], sinrev(acc[nt][rg]), ps[rg]);
            float s = (ps[0] + ps[1]) + (ps[2] + ps[3]);
            s += __shfl_xor(s, 32, 64);
            s += __shfl_xor(s, 16, 64);

            if (kq == 0) {               // 16 lanes store 16 contiguous bf16
                long o = (long)(br * 16 + lr) * 1024 + bc * 32 + ct * 16 + ln;
                Wout[o] = f2bf(s + b3s);
            }
        }
    }
}

// ---------------- stage 2: out = x @ W^T + bias (bf16 MFMA) ----------------
// A = x_bf16 [8192][1024] K-contig; B = W_bf16 [1024][1024] (n=r, k=c) K-contig.
// Block: 256 thr = 4 waves (2x2 of 64x64), tile 128x128, BK=64.
// DOUBLE-BUFFERED: prefetch tile t+1 (global_load_lds) before computing tile
// t; single __syncthreads per tile. LDS 64KB -> 2 blocks/CU.
// Row = 128 B = 8 chunks of 16 B; stored position p holds logical chunk
// p ^ (row&7). Fragment reads hit all 8 positions -> 2 lanes/bank = free.
__global__ __launch_bounds__(256) void gemm_kernel(
        const unsigned short* __restrict__ A,
        const unsigned short* __restrict__ B,
        const float* __restrict__ bias,
        float* __restrict__ C) {
    const int K = 1024;
    __shared__ __align__(16) unsigned short As[2][128 * 64];
    __shared__ __align__(16) unsigned short Bs[2][128 * 64];

    int tid  = threadIdx.x;
    int lane = tid & 63;
    int wv   = tid >> 6;
    int wm   = wv & 1, wn = wv >> 1;
    long Abase = (long)blockIdx.x * 128 * K;
    long Bbase = (long)blockIdx.y * 128 * K;

    int sr8 = tid >> 3;     // staging row 0..31 (+32q)
    int sl  = tid & 7;      // staging chunk slot
    int rsel = lane & 15;   // fragment m/n within 16
    int kq   = lane >> 4;   // fragment k-quad 0..3

    f32x4 acc[4][4] = {};

    auto stage = [&](int kt, int sbuf) {
        #pragma unroll
        for (int q = 0; q < 4; ++q) {
            int row = q * 32 + sr8;
            int cc  = sl ^ (row & 7);                        // global chunk to fetch
            const unsigned short* ga = A + Abase + (long)row * K + kt + cc * 8;
            const unsigned short* gb = B + Bbase + (long)row * K + kt + cc * 8;
            unsigned short* la = &As[sbuf][(q * 256 + wv * 64) * 8];  // wave-uniform base
            unsigned short* lb = &Bs[sbuf][(q * 256 + wv * 64) * 8];
            async_ld16(ga, la);
            async_ld16(gb, lb);
        }
    };

    auto compute = [&](int sbuf) {
        #pragma unroll
        for (int h = 0; h < 2; ++h) {
            bf16x8 af[4], bf[4];
            #pragma unroll
            for (int mi = 0; mi < 4; ++mi) {
                int row = wm * 64 + mi * 16 + rsel;
                int ch  = (h * 4 + kq) ^ (row & 7);
                af[mi] = *(const bf16x8*)&As[sbuf][row * 64 + ch * 8];
            }
            #pragma unroll
            for (int ni = 0; ni < 4; ++ni) {
                int row = wn * 64 + ni * 16 + rsel;
                int ch  = (h * 4 + kq) ^ (row & 7);
                bf[ni] = *(const bf16x8*)&Bs[sbuf][row * 64 + ch * 8];
            }
            #pragma unroll
            for (int mi = 0; mi < 4; ++mi)
                #pragma unroll
                for (int ni = 0; ni < 4; ++ni)
                    acc[mi][ni] = __builtin_amdgcn_mfma_f32_16x16x32_bf16(
                        af[mi], bf[ni], acc[mi][ni], 0, 0, 0);
        }
    };

    stage(0, 0);
    __syncthreads();                 // drain prologue loads
    int buf = 0;
    for (int kt = 64; kt < K; kt += 64) {
        stage(kt, buf ^ 1);          // prefetch next tile (in flight across MFMAs)
        compute(buf);
        __syncthreads();             // all ds_reads of buf done + prefetch landed
        buf ^= 1;
    }
    compute(buf);                    // last tile, no further staging

    // epilogue: C/D layout col=lane&15, row=(lane>>4)*4+reg  (m89/m91 verified)
    int row0 = blockIdx.x * 128 + wm * 64;
    int col0 = blockIdx.y * 128 + wn * 64;
    #pragma unroll
    for (int ni = 0; ni < 4; ++ni) {
        int col = col0 + ni * 16 + rsel;
        float bv = bias[col];
        #pragma unroll
        for (int mi = 0; mi < 4; ++mi) {
            int rbase = row0 + mi * 16 + kq * 4;
            #pragma unroll
            for (int r = 0; r < 4; ++r)
                C[(long)(rbase + r) * 1024 + col] = acc[mi][ni][r] + bv;
        }
    }
}

extern "C" void kernel_launch(void* const* d_in, const int* in_sizes, int n_in,
                              void* d_out, int out_size, void* d_ws, size_t ws_size,
                              hipStream_t stream) {
    const float* x    = (const float*)d_in[0];
    const float* ec   = (const float*)d_in[1];
    const float* W1   = (const float*)d_in[2];
    const float* b1   = (const float*)d_in[3];
    const float* W2   = (const float*)d_in[4];
    const float* b2   = (const float*)d_in[5];
    const float* W3   = (const float*)d_in[6];
    const float* b3   = (const float*)d_in[7];
    const float* bias = (const float*)d_in[8];
    float* out = (float*)d_out;

    unsigned short* xb = (unsigned short*)d_ws;            // 8192*1024 bf16 = 16 MB
    unsigned short* Wb = xb + (size_t)8192 * 1024;         // 1024*1024 bf16 = 2 MB
    float2* SCrow = (float2*)(Wb + (size_t)1024 * 1024);   // 1024*64 float2 = 512 KB
    float2* SCcol = SCrow + 1024 * 64;                     // 1024*64 float2 = 512 KB

    tables_kernel<<<512, 256, 0, stream>>>(ec, W1, b1, SCrow, SCcol);
    fused_cast_siren<<<2048, 256, 0, stream>>>((const float4*)x, xb, SCrow, SCcol,
                                               W2, b2, W3, b3, Wb);
    dim3 g(64, 8);
    gemm_kernel<<<g, 256, 0, stream>>>(xb, Wb, bias, out);
}

// Round 10
// 183.620 us; speedup vs baseline: 1.2656x; 1.2656x over previous
//
#include <hip/hip_runtime.h>
#include <hip/hip_bf16.h>

// SirenLinear: out[b,r] = sum_c x[b,c] * W[r,c] + bias[r]
//   W[r,c] = b3 + h2 . W3,  h2 = sin(30*(W2 h1 + b2)),  h1 = sin(30*(W1 e + b1))
//
// Round-16 (post-mortem r9: identity version SPILLED -- compiler chose
// VGPR=64 under launch_bounds(256,4) and pushed ~74MB to scratch; the
// trans-pipe theory went untested. Third attempt, register-disciplined):
//  * plain __launch_bounds__(256) (r3's identity kernel: VGPR=80, no spill).
//  * h1 computed INLINE from LDS float2 reads (no 32-float staging arrays).
//  * W2->bf16 conversion hoisted to tables_kernel (W2bf, done once, not
//    per-block): fused prologue = 8 vector loads, no pack VALU.
//  * r8 MFMA-swap layout, T14 cast split, zcol XOR-swizzle (numerics
//    validated by r9 pass), gemm: all unchanged.

typedef __attribute__((ext_vector_type(8))) short bf16x8;
typedef __attribute__((ext_vector_type(4))) float f32x4;

#define SIN_SCALE 4.77464829275686f   // 30 / (2*pi)

__device__ __forceinline__ unsigned short f2bf(float f) {
    union { float f; unsigned u; } v; v.f = f;
    unsigned r = v.u + 0x7fffu + ((v.u >> 16) & 1u);   // RNE
    return (unsigned short)(r >> 16);
}

// pack 2 floats -> 2 bf16 by truncation (cheap; RNE kept for final store)
__device__ __forceinline__ unsigned pktrunc(float a, float b) {
    union { float f; unsigned u; } x, y; x.f = a; y.f = b;
    return (x.u >> 16) | (y.u & 0xffff0000u);
}

// sin/cos(2*pi*x) -- raw v_sin/v_cos, valid |x| <= 256 revs (here |x| <= ~14)
__device__ __forceinline__ float sinrev(float x) {
    return __builtin_amdgcn_sinf(x);
}
__device__ __forceinline__ float cosrev(float x) {
    return __builtin_amdgcn_cosf(x);
}

__device__ __forceinline__ void async_ld16(const void* g, void* l) {
    __builtin_amdgcn_global_load_lds(
        (__attribute__((address_space(1))) void*)g,
        (__attribute__((address_space(3))) void*)l, 16, 0, 0);
}

// ---------------- stage 0: layer-1 sin/cos tables + W2/b2 pre-scale --------
// blocks [0,512): SCrow[r][j]={sin,cos}(2pi*zrow), SCcol[c][j] likewise,
//   zrow[r][j]=S*(W1[j,:].e(r,0)+b1[j]); zcol[c][j]=S*(W1[j,:].(e(0,c)-e(0,0)))
// block 512: W2bf = trunc-bf16(S*W2) (bit-identical to old per-block pktrunc);
//   b2s = S*b2 (f32).
__global__ __launch_bounds__(256) void tables_kernel(
        const float* __restrict__ ec,
        const float* __restrict__ W1, const float* __restrict__ b1,
        const float* __restrict__ W2, const float* __restrict__ b2,
        float2* __restrict__ SCrow, float2* __restrict__ SCcol,
        unsigned short* __restrict__ W2bf, float* __restrict__ b2s) {
    if (blockIdx.x == 512) {
        int tid = threadIdx.x;
        #pragma unroll
        for (int q = 0; q < 16; ++q) {
            int i = q * 256 + tid;                    // 0..4095
            unsigned u = __float_as_uint(SIN_SCALE * W2[i]);
            W2bf[i] = (unsigned short)(u >> 16);      // truncation == pktrunc
        }
        if (tid < 64) b2s[tid] = SIN_SCALE * b2[tid];
        return;
    }
    int idx = blockIdx.x * 256 + threadIdx.x;    // 0..131071
    int j = idx & 63;
    int t = idx >> 6;                            // 0..2047
    const float* wr = W1 + j * 18;
    if (t < 1024) {
        const float* pe = ec + (long)t * 1024 * 18;   // point (r=t, c=0)
        float z = b1[j];
        #pragma unroll
        for (int i = 0; i < 18; ++i) z += wr[i] * pe[i];
        z *= SIN_SCALE;
        SCrow[t * 64 + j] = make_float2(sinrev(z), cosrev(z));
    } else {
        int c = t - 1024;
        const float* pe = ec + (long)c * 18;          // point (r=0, c)
        float z = 0.f;
        #pragma unroll
        for (int i = 0; i < 18; ++i) z += wr[i] * (pe[i] - ec[i]);
        z *= SIN_SCALE;
        SCcol[c * 64 + j] = make_float2(sinrev(z), cosrev(z));
    }
}

// ---------------- stage 1: [generate W, LDS-tiled] + [x cast share] --------
// 2048 blocks, ALL identical: block sb covers W rows [br*16,+16) x cols
// [bc*32,+32) AND casts x float4s [sb*1024,+1024) (T14 split).
//
// LDS: SCrow tile 16x64 float2 (8KB, linear); SCcol tile 32x64 float2
// (16KB). SCcol rows = 512B = 32 chunks of 16B; physical chunk p holds
// logical chunk (p&16)|((p&15)^(col&15)) (source pre-swizzled, m104/m173).
// Compute read: lane (ln,kq), col cl=ct*16+ln reads phys chunks
// (kq*4+t)^sx and 16|((kq*4+t)^sx): 16 distinct chunks across 16 lanes,
// banks p*4%32 -> 2-way = free (m136).
// h1 = sr*cc + cr*sc computed INLINE (2 float2 live temps, no arrays).
// h1 frag (MFMA B operand): lane ln = point, k = kc*32+kq*8+j.
// W2 frag (A operand, preloaded from W2bf): lane ln = unit-within-subtile.
// C/D [m89/m91]: n=ln=point, m=kq*4+rg -> unit=nt*16+kq*4+rg.
// acc init = b2s[unit]; layer-2: in-lane 16 sin+fma (4 partials),
// ^32/^16 shfl reduce over kq, kq==0 lanes store 16 contiguous bf16.
__global__ __launch_bounds__(256) void fused_cast_siren(
        const float4* __restrict__ x, unsigned short* __restrict__ xb,
        const float2* __restrict__ SCrow, const float2* __restrict__ SCcol,
        const unsigned short* __restrict__ W2bf, const float* __restrict__ b2s,
        const float* __restrict__ W3, const float* __restrict__ b3,
        unsigned short* __restrict__ Wout) {
    __shared__ __align__(16) float2 zrow_l[16 * 64];   // 8 KB, linear
    __shared__ __align__(16) float2 zcol_l[32 * 64];   // 16 KB, chunk-swizzled

    int tid  = threadIdx.x;
    int sb   = blockIdx.x;             // 0..2047
    int lane = tid & 63;
    int wv   = tid >> 6;
    int ln   = lane & 15;
    int kq   = lane >> 4;

    int br = sb & 63;                  // row-tile: rows [br*16, br*16+16)
    int bc = sb >> 6;                  // col-tile: cols [bc*32, bc*32+32)

    long ci = (long)sb * 1024 + tid;

    // ---- cast half 1: issue loads (latency hides under table staging) ----
    float4 cv0 = x[ci];
    float4 cv1 = x[ci + 256];

    // ---- stage tables into LDS (6 x global_load_lds per thread) ----
    {
        const float* rs = (const float*)SCrow + (long)br * 16 * 128;
        #pragma unroll
        for (int q = 0; q < 2; ++q) {
            int idx = q * 256 + tid;                  // chunk 0..511
            async_ld16(rs + idx * 4, (float*)zrow_l + (q * 256 + wv * 64) * 4);
        }
        #pragma unroll
        for (int q = 0; q < 4; ++q) {
            int P  = q * 256 + tid;                   // physical chunk 0..1023
            int cr = P >> 5;                          // local col 0..31
            int pc = P & 31;
            int lc = (pc & 16) | ((pc & 15) ^ (cr & 15));  // logical chunk
            const float* src = (const float*)SCcol + (long)(bc * 32 + cr) * 128 + lc * 4;
            async_ld16(src, (float*)zcol_l + (q * 256 + wv * 64) * 4);
        }
    }

    // ---- cast half 1: cvt + store; half 2: issue loads ----
    {
        ushort4 o;
        o.x = f2bf(cv0.x); o.y = f2bf(cv0.y); o.z = f2bf(cv0.z); o.w = f2bf(cv0.w);
        *(ushort4*)(xb + ci * 4) = o;
        o.x = f2bf(cv1.x); o.y = f2bf(cv1.y); o.z = f2bf(cv1.z); o.w = f2bf(cv1.w);
        *(ushort4*)(xb + (ci + 256) * 4) = o;
    }
    float4 cv2 = x[ci + 512];
    float4 cv3 = x[ci + 768];

    // ---- preload A-frags from W2bf (pre-scaled trunc bf16); b2s/W3 f32 ----
    bf16x8 wfrag[2][4];
    #pragma unroll
    for (int kc = 0; kc < 2; ++kc)
        #pragma unroll
        for (int nt = 0; nt < 4; ++nt)
            wfrag[kc][nt] = *(const bf16x8*)(W2bf + (nt * 16 + ln) * 64 + kc * 32 + kq * 8);
    f32x4 b2x4[4], w3x4[4];
    #pragma unroll
    for (int nt = 0; nt < 4; ++nt) {
        float4 bb = *(const float4*)(b2s + nt * 16 + kq * 4);
        float4 ww = *(const float4*)(W3 + nt * 16 + kq * 4);
        b2x4[nt][0] = bb.x; b2x4[nt][1] = bb.y; b2x4[nt][2] = bb.z; b2x4[nt][3] = bb.w;
        w3x4[nt][0] = ww.x; w3x4[nt][1] = ww.y; w3x4[nt][2] = ww.z; w3x4[nt][3] = ww.w;
    }
    float b3s = b3[0];

    // ---- cast half 2: cvt + store (regs die before compute phase) ----
    {
        ushort4 o;
        o.x = f2bf(cv2.x); o.y = f2bf(cv2.y); o.z = f2bf(cv2.z); o.w = f2bf(cv2.w);
        *(ushort4*)(xb + (ci + 512) * 4) = o;
        o.x = f2bf(cv3.x); o.y = f2bf(cv3.y); o.z = f2bf(cv3.z); o.w = f2bf(cv3.w);
        *(ushort4*)(xb + (ci + 768) * 4) = o;
    }

    __syncthreads();                    // tables resident in LDS

    #pragma unroll
    for (int lr4 = 0; lr4 < 4; ++lr4) {
        int lr = wv * 4 + lr4;                            // local row 0..15
        const float2* zb = zrow_l + lr * 64 + kq * 8;     // broadcast reads
        float sr0[8], cr0[8], sr1[8], cr1[8];
        #pragma unroll
        for (int j = 0; j < 8; ++j) {
            float2 t0 = zb[j];      sr0[j] = t0.x; cr0[j] = t0.y;
            float2 t1 = zb[32 + j]; sr1[j] = t1.x; cr1[j] = t1.y;
        }

        #pragma unroll
        for (int ct = 0; ct < 2; ++ct) {
            int cl = ct * 16 + ln;                        // local col 0..31
            const float2* cb2 = zcol_l + cl * 64;
            int sx = cl & 15;

            // h1 = sr*cc + cr*sc, computed inline and packed immediately
            union { bf16x8 v; unsigned u[4]; } a0, a1;
            #pragma unroll
            for (int t = 0; t < 4; ++t) {
                int p0 = (((kq * 4 + t) ^ sx)) * 2;       // float2 idx of chunk
                int p1 = ((16 | ((kq * 4 + t) ^ sx))) * 2;
                float h0[2], h1v[2];
                #pragma unroll
                for (int e = 0; e < 2; ++e) {
                    int j = t * 2 + e;
                    float2 c0 = cb2[p0 + e];
                    float2 c1 = cb2[p1 + e];
                    h0[e]  = fmaf(sr0[j], c0.y, cr0[j] * c0.x);
                    h1v[e] = fmaf(sr1[j], c1.y, cr1[j] * c1.x);
                }
                a0.u[t] = pktrunc(h0[0], h0[1]);
                a1.u[t] = pktrunc(h1v[0], h1v[1]);
            }

            // acc init = S*b2[unit]; D[m=unit-in-subtile, n=point]
            f32x4 acc[4];
            #pragma unroll
            for (int nt = 0; nt < 4; ++nt) acc[nt] = b2x4[nt];
            #pragma unroll
            for (int nt = 0; nt < 4; ++nt) {
                acc[nt] = __builtin_amdgcn_mfma_f32_16x16x32_bf16(wfrag[0][nt], a0.v, acc[nt], 0, 0, 0);
                acc[nt] = __builtin_amdgcn_mfma_f32_16x16x32_bf16(wfrag[1][nt], a1.v, acc[nt], 0, 0, 0);
            }

            // layer-2: in-lane 16 sin+fma with 4 partial sums, reduce over kq
            float ps[4] = {0.f, 0.f, 0.f, 0.f};
            #pragma unroll
            for (int nt = 0; nt < 4; ++nt)
                #pragma unroll
                for (int rg = 0; rg < 4; ++rg)
                    ps[rg] = fmaf(w3x4[nt][rg], sinrev(acc[nt][rg]), ps[rg]);
            float s = (ps[0] + ps[1]) + (ps[2] + ps[3]);
            s += __shfl_xor(s, 32, 64);
            s += __shfl_xor(s, 16, 64);

            if (kq == 0) {               // 16 lanes store 16 contiguous bf16
                long o = (long)(br * 16 + lr) * 1024 + bc * 32 + ct * 16 + ln;
                Wout[o] = f2bf(s + b3s);
            }
        }
    }
}

// ---------------- stage 2: out = x @ W^T + bias (bf16 MFMA) ----------------
// A = x_bf16 [8192][1024] K-contig; B = W_bf16 [1024][1024] (n=r, k=c) K-contig.
// Block: 256 thr = 4 waves (2x2 of 64x64), tile 128x128, BK=64.
// DOUBLE-BUFFERED: prefetch tile t+1 (global_load_lds) before computing tile
// t; single __syncthreads per tile. LDS 64KB -> 2 blocks/CU.
// Row = 128 B = 8 chunks of 16 B; stored position p holds logical chunk
// p ^ (row&7). Fragment reads hit all 8 positions -> 2 lanes/bank = free.
__global__ __launch_bounds__(256) void gemm_kernel(
        const unsigned short* __restrict__ A,
        const unsigned short* __restrict__ B,
        const float* __restrict__ bias,
        float* __restrict__ C) {
    const int K = 1024;
    __shared__ __align__(16) unsigned short As[2][128 * 64];
    __shared__ __align__(16) unsigned short Bs[2][128 * 64];

    int tid  = threadIdx.x;
    int lane = tid & 63;
    int wv   = tid >> 6;
    int wm   = wv & 1, wn = wv >> 1;
    long Abase = (long)blockIdx.x * 128 * K;
    long Bbase = (long)blockIdx.y * 128 * K;

    int sr8 = tid >> 3;     // staging row 0..31 (+32q)
    int sl  = tid & 7;      // staging chunk slot
    int rsel = lane & 15;   // fragment m/n within 16
    int kq   = lane >> 4;   // fragment k-quad 0..3

    f32x4 acc[4][4] = {};

    auto stage = [&](int kt, int sbuf) {
        #pragma unroll
        for (int q = 0; q < 4; ++q) {
            int row = q * 32 + sr8;
            int cc  = sl ^ (row & 7);                        // global chunk to fetch
            const unsigned short* ga = A + Abase + (long)row * K + kt + cc * 8;
            const unsigned short* gb = B + Bbase + (long)row * K + kt + cc * 8;
            unsigned short* la = &As[sbuf][(q * 256 + wv * 64) * 8];  // wave-uniform base
            unsigned short* lb = &Bs[sbuf][(q * 256 + wv * 64) * 8];
            async_ld16(ga, la);
            async_ld16(gb, lb);
        }
    };

    auto compute = [&](int sbuf) {
        #pragma unroll
        for (int h = 0; h < 2; ++h) {
            bf16x8 af[4], bf[4];
            #pragma unroll
            for (int mi = 0; mi < 4; ++mi) {
                int row = wm * 64 + mi * 16 + rsel;
                int ch  = (h * 4 + kq) ^ (row & 7);
                af[mi] = *(const bf16x8*)&As[sbuf][row * 64 + ch * 8];
            }
            #pragma unroll
            for (int ni = 0; ni < 4; ++ni) {
                int row = wn * 64 + ni * 16 + rsel;
                int ch  = (h * 4 + kq) ^ (row & 7);
                bf[ni] = *(const bf16x8*)&Bs[sbuf][row * 64 + ch * 8];
            }
            #pragma unroll
            for (int mi = 0; mi < 4; ++mi)
                #pragma unroll
                for (int ni = 0; ni < 4; ++ni)
                    acc[mi][ni] = __builtin_amdgcn_mfma_f32_16x16x32_bf16(
                        af[mi], bf[ni], acc[mi][ni], 0, 0, 0);
        }
    };

    stage(0, 0);
    __syncthreads();                 // drain prologue loads
    int buf = 0;
    for (int kt = 64; kt < K; kt += 64) {
        stage(kt, buf ^ 1);          // prefetch next tile (in flight across MFMAs)
        compute(buf);
        __syncthreads();             // all ds_reads of buf done + prefetch landed
        buf ^= 1;
    }
    compute(buf);                    // last tile, no further staging

    // epilogue: C/D layout col=lane&15, row=(lane>>4)*4+reg  (m89/m91 verified)
    int row0 = blockIdx.x * 128 + wm * 64;
    int col0 = blockIdx.y * 128 + wn * 64;
    #pragma unroll
    for (int ni = 0; ni < 4; ++ni) {
        int col = col0 + ni * 16 + rsel;
        float bv = bias[col];
        #pragma unroll
        for (int mi = 0; mi < 4; ++mi) {
            int rbase = row0 + mi * 16 + kq * 4;
            #pragma unroll
            for (int r = 0; r < 4; ++r)
                C[(long)(rbase + r) * 1024 + col] = acc[mi][ni][r] + bv;
        }
    }
}

extern "C" void kernel_launch(void* const* d_in, const int* in_sizes, int n_in,
                              void* d_out, int out_size, void* d_ws, size_t ws_size,
                              hipStream_t stream) {
    const float* x    = (const float*)d_in[0];
    const float* ec   = (const float*)d_in[1];
    const float* W1   = (const float*)d_in[2];
    const float* b1   = (const float*)d_in[3];
    const float* W2   = (const float*)d_in[4];
    const float* b2   = (const float*)d_in[5];
    const float* W3   = (const float*)d_in[6];
    const float* b3   = (const float*)d_in[7];
    const float* bias = (const float*)d_in[8];
    float* out = (float*)d_out;

    unsigned short* xb = (unsigned short*)d_ws;            // 8192*1024 bf16 = 16 MB
    unsigned short* Wb = xb + (size_t)8192 * 1024;         // 1024*1024 bf16 = 2 MB
    float2* SCrow = (float2*)(Wb + (size_t)1024 * 1024);   // 1024*64 float2 = 512 KB
    float2* SCcol = SCrow + 1024 * 64;                     // 1024*64 float2 = 512 KB
    unsigned short* W2bf = (unsigned short*)(SCcol + 1024 * 64);  // 4096 bf16 = 8 KB
    float* b2s = (float*)(W2bf + 4096);                    // 64 f32

    tables_kernel<<<513, 256, 0, stream>>>(ec, W1, b1, W2, b2, SCrow, SCcol, W2bf, b2s);
    fused_cast_siren<<<2048, 256, 0, stream>>>((const float4*)x, xb, SCrow, SCcol,
                                               W2bf, b2s, W3, b3, Wb);
    dim3 g(64, 8);
    gemm_kernel<<<g, 256, 0, stream>>>(xb, Wb, bias, out);
}